// Round 6
// baseline (453.982 us; speedup 1.0000x reference)
//
#include <hip/hip_runtime.h>
#include <cstdint>
#include <cstddef>

#define M_DIM 4096
#define K_DIM 4096
#define N_DIM 8192
#define NKT (K_DIM / 128)  // 32 K-tiles of BK=128 bytes

typedef int v4i __attribute__((ext_vector_type(4)));
typedef int v16i __attribute__((ext_vector_type(16)));

__device__ __forceinline__ void load_lds16(const void* g, void* l) {
  __builtin_amdgcn_global_load_lds(
      (const __attribute__((address_space(1))) void*)g,
      (__attribute__((address_space(3))) void*)l,
      16, 0, 0);
}

#define FENCE() asm volatile("" ::: "memory")
#define BARRIER()                      \
  do {                                 \
    FENCE();                           \
    __builtin_amdgcn_s_barrier();      \
    FENCE();                           \
  } while (0)
#define VMCNT(n) asm volatile("s_waitcnt vmcnt(" #n ")" ::: "memory")
#define LGKM0() asm volatile("s_waitcnt lgkmcnt(0)" ::: "memory")

__device__ __forceinline__ uint32_t pack4(int4 v) {
  return ((uint32_t)v.x & 0xFFu) | (((uint32_t)v.y & 0xFFu) << 8) |
         (((uint32_t)v.z & 0xFFu) << 16) | ((uint32_t)v.w << 24);
}

// ---------------------------------------------------------------------------
// A int32 [M][K] -> A8 int8 [M][K].
// ---------------------------------------------------------------------------
__global__ __launch_bounds__(256) void pack_a_kernel(const int* __restrict__ A32,
                                                     uint8_t* __restrict__ A8) {
  const int n16 = (M_DIM * K_DIM) / 16;
  const int stride = gridDim.x * 256;
  for (int i = blockIdx.x * 256 + threadIdx.x; i < n16; i += stride) {
    const int4* src = reinterpret_cast<const int4*>(A32) + (size_t)i * 4;
    int4 o;
    o.x = (int)pack4(src[0]);
    o.y = (int)pack4(src[1]);
    o.z = (int)pack4(src[2]);
    o.w = (int)pack4(src[3]);
    reinterpret_cast<int4*>(A8)[i] = o;
  }
}

// ---------------------------------------------------------------------------
// B int32 [K][N] -> Bt int8 [N][K]. 128x128 tiles through LDS; stage-2
// remap gives full-cacheline Bt stores (lanes 0..7 = one 128B row).
// ---------------------------------------------------------------------------
#define TPITCH 132
__global__ __launch_bounds__(256) void pack_bt_kernel(const int* __restrict__ B32,
                                                      uint8_t* __restrict__ Bt) {
  __shared__ uint8_t tile[128 * TPITCH];
  const int t = threadIdx.x;
  const int n0 = blockIdx.x * 128;
  const int k0 = blockIdx.y * 128;

#pragma unroll
  for (int c = 0; c < 16; ++c) {
    const int chunk = c * 256 + t;  // 0..4095, 4 int32 each
    const int row = chunk >> 5;     // k-row 0..127
    const int nc4 = (chunk & 31);   // n-dword 0..31
    const int4 v = *reinterpret_cast<const int4*>(
        B32 + (size_t)(k0 + row) * N_DIM + n0 + nc4 * 4);
    *reinterpret_cast<uint32_t*>(&tile[row * TPITCH + nc4 * 4]) = pack4(v);
  }
  __syncthreads();

  const int kc = (t & 7) << 4;   // 0..112
  const int nb = (t >> 3) << 2;  // 0..124
  uint32_t dw[16];
#pragma unroll
  for (int j = 0; j < 16; ++j)
    dw[j] = *reinterpret_cast<const uint32_t*>(&tile[(kc + j) * TPITCH + nb]);

#pragma unroll
  for (int np = 0; np < 4; ++np) {
    const uint32_t sel = (uint32_t)np | (((uint32_t)np + 4u) << 8);
    uint32_t o[4];
#pragma unroll
    for (int d = 0; d < 4; ++d) {
      const uint32_t p01 = __builtin_amdgcn_perm(dw[4 * d + 1], dw[4 * d + 0], sel);
      const uint32_t p23 = __builtin_amdgcn_perm(dw[4 * d + 3], dw[4 * d + 2], sel);
      o[d] = __builtin_amdgcn_perm(p23, p01, 0x05040100u);
    }
    const int4 v = make_int4((int)o[0], (int)o[1], (int)o[2], (int)o[3]);
    *reinterpret_cast<int4*>(Bt + (size_t)(n0 + nb + np) * K_DIM + k0 + kc) = v;
  }
}

// ---------------------------------------------------------------------------
// 256x256 8-phase i8 GEMM, mfma_i32_32x32x32_i8 (4404 TOPS pipe).
// 512 threads = 8 waves (2m x 4n), per-wave out 128x64 = 4x2 frags of 32x32.
// ALL 24 ds_read_b128 hoisted to tile top -> compiler's counted lgkmcnt lets
// q1-q3 reads complete under q0-q2 MFMA (read/MFMA overlap). Safety:
//  - A[T+1] stages -> buf^1 (never read this tile).
//  - B[T+2] stages -> lds[BUF][1]: explicit lgkmcnt(0) before P1's closing
//    barrier guarantees every wave's B reads (incl. bF[1], unreferenced by
//    q0/q1) completed before any wave issues a B stage in P2/P3.
//  - vmcnt ledger identical to round-4 (verified): stages never skipped,
//    tail clamped; P3's vmcnt(2) lands A[T+1]+B[T+1] before next tile.
// ---------------------------------------------------------------------------
__global__ __launch_bounds__(512, 2) void gemm_i8_kernel(
    const uint8_t* __restrict__ A, const uint8_t* __restrict__ Bt,
    const float* __restrict__ scale, float* __restrict__ C) {
  __shared__ uint8_t lds[2][2][2][128 * 128];  // [buf][A/B][half][16KB]

  const int tid = threadIdx.x;
  const int l = tid & 63;
  const int wave = tid >> 6;
  const int wr = wave >> 2;  // m-half 0..1
  const int wc = wave & 3;   // n-quarter 0..3

  // bijective XCD swizzle over 512 blocks (64 per XCD, 2 full tile-rows each)
  int lin = blockIdx.y * (N_DIM / 256) + blockIdx.x;
  lin = (lin & 7) * 64 + (lin >> 3);
  const int bx = lin & 31;
  const int by = lin >> 5;
  const int m0 = by * 256;
  const int n0 = bx * 256;

  // staging geometry: chunk q*512+tid, r=chunk>>3, s=chunk&7, src c16 = s^(r&7)
  const int r0 = tid >> 3;
  const int r1 = (512 + tid) >> 3;
  const int s0 = tid & 7;
  const int c0 = ((s0 ^ (r0 & 7)) << 4);
  const int c1 = ((s0 ^ (r1 & 7)) << 4);
  const uint8_t* Abase = A + (size_t)m0 * K_DIM;
  const uint8_t* Bbase = Bt + (size_t)n0 * K_DIM;

#define STAGE(OP, BASE, BUF, HALF, T)                                                \
  do {                                                                               \
    load_lds16((BASE) + (size_t)((HALF)*128 + r0) * K_DIM + (T)*128 + c0,            \
               &lds[BUF][OP][HALF][tid * 16]);                                       \
    load_lds16((BASE) + (size_t)((HALF)*128 + r1) * K_DIM + (T)*128 + c1,            \
               &lds[BUF][OP][HALF][(512 + tid) * 16]);                               \
  } while (0)

  // 32x32x32 A/B frag: lane reads 16B at row=(l&31)+32*mb, k-chunk c16=ks*2+(l>>5)
  const int l31 = l & 31;
  const int rb = l31 * 128;
  const int hb = l >> 5;
  int swz[4];
#pragma unroll
  for (int ks = 0; ks < 4; ++ks) swz[ks] = ((ks * 2 + hb) ^ (l & 7)) << 4;
  const int brb = (wc & 1) * 64 * 128;  // wave's 64-row offset within its B-half

  v16i acc[4][2];
#pragma unroll
  for (int i = 0; i < 4; ++i)
#pragma unroll
    for (int j = 0; j < 2; ++j)
#pragma unroll
      for (int r = 0; r < 16; ++r) acc[i][j][r] = 0;

  // prologue: A[0], B[0] -> buf0; B[1] -> buf1
  STAGE(0, Abase, 0, 0, 0);
  STAGE(0, Abase, 0, 1, 0);
  STAGE(1, Bbase, 0, 0, 0);
  STAGE(1, Bbase, 0, 1, 0);
  STAGE(1, Bbase, 1, 0, 1);
  STAGE(1, Bbase, 1, 1, 1);
  VMCNT(4);  // A[0], B[0] landed; B[1] may remain in flight
  BARRIER();

#define MFMA_Q(MB0, NB)                                                             \
  do {                                                                              \
    __builtin_amdgcn_s_setprio(1);                                                  \
    _Pragma("unroll") for (int mm = 0; mm < 2; ++mm)                                \
        _Pragma("unroll") for (int ks = 0; ks < 4; ++ks) {                          \
      acc[(MB0) + mm][NB] = __builtin_amdgcn_mfma_i32_32x32x32_i8(                  \
          aF[(MB0) + mm][ks], bF[NB][ks], acc[(MB0) + mm][NB], 0, 0, 0);            \
    }                                                                               \
    __builtin_amdgcn_s_setprio(0);                                                  \
    __builtin_amdgcn_sched_barrier(0);                                              \
  } while (0)

#define DO_TILE(T, BUF)                                                             \
  do {                                                                              \
    const int TA = ((T) + 1 < NKT) ? (T) + 1 : NKT - 1; /* clamp: keep ledger */    \
    const int TB = ((T) + 2 < NKT) ? (T) + 2 : NKT - 1; /* identical at tail */     \
    const uint8_t* _As = &lds[BUF][0][wr][0];                                       \
    const uint8_t* _Bs = &lds[BUF][1][wc >> 1][0];                                   \
    v4i aF[4][4]; /* [mb][ks] */                                                    \
    v4i bF[2][4]; /* [nb][ks] */                                                    \
    /* ---- all 24 reads upfront, q0's 12 first ---- */                             \
    _Pragma("unroll") for (int mb = 0; mb < 2; ++mb)                                \
        _Pragma("unroll") for (int ks = 0; ks < 4; ++ks)                            \
            aF[mb][ks] = *(const v4i*)&_As[mb * 4096 + rb + swz[ks]];               \
    _Pragma("unroll") for (int ks = 0; ks < 4; ++ks)                                \
        bF[0][ks] = *(const v4i*)&_Bs[brb + rb + swz[ks]];                          \
    _Pragma("unroll") for (int mb = 2; mb < 4; ++mb)                                \
        _Pragma("unroll") for (int ks = 0; ks < 4; ++ks)                            \
            aF[mb][ks] = *(const v4i*)&_As[mb * 4096 + rb + swz[ks]];               \
    _Pragma("unroll") for (int ks = 0; ks < 4; ++ks)                                \
        bF[1][ks] = *(const v4i*)&_Bs[brb + 4096 + rb + swz[ks]];                   \
    /* ---- P0: stage A[TA]h0; MFMA q0 (mb01 x nb0) ---- */                         \
    STAGE(0, Abase, (BUF) ^ 1, 0, TA);                                              \
    BARRIER();                                                                      \
    MFMA_Q(0, 0);                                                                   \
    BARRIER();                                                                      \
    /* ---- P1: stage A[TA]h1; MFMA q1 (mb23 x nb0); drain lgkm ---- */             \
    STAGE(0, Abase, (BUF) ^ 1, 1, TA);                                              \
    BARRIER();                                                                      \
    MFMA_Q(2, 0);                                                                   \
    LGKM0(); /* all B reads done on every wave before any B stage below */          \
    BARRIER();                                                                      \
    /* ---- P2: stage B[TB]h0; MFMA q2 (mb01 x nb1) ---- */                         \
    STAGE(1, Bbase, BUF, 0, TB);                                                    \
    BARRIER();                                                                      \
    MFMA_Q(0, 1);                                                                   \
    BARRIER();                                                                      \
    /* ---- P3: vmcnt(2) [lands A[T+1],B[T+1]]; stage B[TB]h1; MFMA q3 ---- */      \
    VMCNT(2);                                                                       \
    STAGE(1, Bbase, BUF, 1, TB);                                                    \
    BARRIER();                                                                      \
    MFMA_Q(2, 1);                                                                   \
    BARRIER();                                                                      \
  } while (0)

  for (int t = 0; t < NKT; t += 2) {
    DO_TILE(t, 0);
    DO_TILE(t + 1, 1);
  }

  // epilogue: 32x32 C/D frag: col = l&31, row = (reg&3) + 8*(reg>>2) + 4*(l>>5)
  // (m74/m101-verified, dtype-independent). Nontemporal: C never re-read;
  // keep LLC for A8/Bt.
  const int colbase = n0 + wc * 64 + l31;
  const int rowbase = m0 + wr * 128 + 4 * hb;
#pragma unroll
  for (int nb = 0; nb < 2; ++nb) {
    const int col = colbase + nb * 32;
    const float s = scale[col];
#pragma unroll
    for (int mb = 0; mb < 4; ++mb) {
#pragma unroll
      for (int r = 0; r < 16; ++r) {
        const int row = rowbase + mb * 32 + (r & 3) + 8 * (r >> 2);
        __builtin_nontemporal_store((float)acc[mb][nb][r] * s,
                                    &C[(size_t)row * N_DIM + col]);
      }
    }
  }
#undef DO_TILE
#undef MFMA_Q
#undef STAGE
}

// ---------------------------------------------------------------------------
// Fallback (ws too small) — correct but slow.
// ---------------------------------------------------------------------------
__global__ __launch_bounds__(256) void gemm_fallback(const int* __restrict__ A,
                                                     const int* __restrict__ B,
                                                     const float* __restrict__ scale,
                                                     float* __restrict__ C) {
  const int col = blockIdx.x * 16 + (threadIdx.x & 15);
  const int row = blockIdx.y * 16 + (threadIdx.x >> 4);
  int acc = 0;
  for (int k = 0; k < K_DIM; k += 4) {
    const int4 a = *reinterpret_cast<const int4*>(&A[(size_t)row * K_DIM + k]);
    acc += a.x * B[(size_t)(k + 0) * N_DIM + col];
    acc += a.y * B[(size_t)(k + 1) * N_DIM + col];
    acc += a.z * B[(size_t)(k + 2) * N_DIM + col];
    acc += a.w * B[(size_t)(k + 3) * N_DIM + col];
  }
  C[(size_t)row * N_DIM + col] = (float)acc * scale[col];
}

extern "C" void kernel_launch(void* const* d_in, const int* in_sizes, int n_in,
                              void* d_out, int out_size, void* d_ws, size_t ws_size,
                              hipStream_t stream) {
  const int* A32 = (const int*)d_in[0];
  const int* B32 = (const int*)d_in[1];
  const float* scale = (const float*)d_in[2];
  float* C = (float*)d_out;

  const size_t btBytes = (size_t)K_DIM * N_DIM;  // 32 MB
  const size_t a8Bytes = (size_t)M_DIM * K_DIM;  // 16 MB
  if (ws_size >= btBytes + a8Bytes) {
    uint8_t* Bt = (uint8_t*)d_ws;
    uint8_t* A8 = (uint8_t*)d_ws + btBytes;
    pack_a_kernel<<<2048, 256, 0, stream>>>(A32, A8);
    pack_bt_kernel<<<dim3(N_DIM / 128, K_DIM / 128), 256, 0, stream>>>(B32, Bt);
    gemm_i8_kernel<<<dim3(N_DIM / 256, M_DIM / 256), 512, 0, stream>>>(
        A8, Bt, scale, C);
  } else {
    gemm_fallback<<<dim3(N_DIM / 16, M_DIM / 16), 256, 0, stream>>>(
        A32, B32, scale, C);
  }
}